// Round 1
// baseline (146.844 us; speedup 1.0000x reference)
//
#include <hip/hip_runtime.h>
#include <stdint.h>

// Problem: S=4096, D=64
//   qk = (Q @ K^T) * 8
//   t  = qk * ((u >= 0.1) / 0.9)
//   r  = floor(t * rr[i])            (rr broadcasts over cols)
//   out = (t * r / sum(r)) @ V
// Restructure: U = (t*r) @ V and R = sum(r) in ONE fused pass (no S*S
// materialization, u_drop read exactly once), then out = U / R.

#define S 4096
#define D 64
#define MT 64            // i-rows per block
#define JT 64            // j per tile
#define NCHUNK 8         // j-chunks (grid = 64 * NCHUNK = 512 blocks)
#define JCHUNK (S / NCHUNK)
#define NTILES (JCHUNK / JT)
#define LDP 72           // LDS padded row length (shorts): 144B rows -> 2-way conflicts only (free)

typedef float f32x4 __attribute__((ext_vector_type(4)));
typedef short s16x8 __attribute__((ext_vector_type(8)));
typedef unsigned short u16x4 __attribute__((ext_vector_type(4)));

// fp32 -> bf16, round-to-nearest-even (inputs are finite; no NaN path needed)
__device__ inline unsigned short f2bf(float f) {
    union { float f; unsigned u; } v; v.f = f;
    unsigned r = v.u + 0x7fffu + ((v.u >> 16) & 1u);
    return (unsigned short)(r >> 16);
}

__launch_bounds__(256, 2)
__global__ void fused_kernel(const float* __restrict__ Q,
                             const float* __restrict__ Kf,
                             const float* __restrict__ V,
                             const float* __restrict__ Ud,
                             const float* __restrict__ RR,
                             float* __restrict__ out,   // pre-zeroed; fp32 atomic accumulate
                             int* __restrict__ sumr)    // pre-zeroed
{
    __shared__ short kb[64 * LDP];        // K tile, row-major [j][k], bf16
    __shared__ short vt[64 * LDP];        // V tile transposed [d][j], bf16
    __shared__ short pb[4 * 16 * LDP];    // per-wave P relayout buffer [16][64]
    __shared__ int red[4];

    const int tid  = threadIdx.x;
    const int w    = tid >> 6;            // wave 0..3
    const int lane = tid & 63;
    const int quad = lane >> 4;
    const int n16  = lane & 15;

    const int ib = blockIdx.x & (S / MT - 1);   // i-block 0..63
    const int ic = blockIdx.x / (S / MT);       // j-chunk 0..NCHUNK-1
    const int i0w = ib * MT + w * 16;           // this wave's 16 Q-rows

    // --- Q A-fragments (2 K-steps of 32), fp32 -> bf16, kept in regs all kernel ---
    // A-layout: A[m=lane&15][k = ks*32 + quad*8 + jj]
    s16x8 aQ[2];
    {
        const float* qrow = Q + (size_t)(i0w + n16) * D;
        for (int ks = 0; ks < 2; ++ks) {
            const float* p = qrow + ks * 32 + quad * 8;
            float4 q0 = *(const float4*)(p);
            float4 q1 = *(const float4*)(p + 4);
            s16x8 a;
            a[0] = (short)f2bf(q0.x); a[1] = (short)f2bf(q0.y);
            a[2] = (short)f2bf(q0.z); a[3] = (short)f2bf(q0.w);
            a[4] = (short)f2bf(q1.x); a[5] = (short)f2bf(q1.y);
            a[6] = (short)f2bf(q1.z); a[7] = (short)f2bf(q1.w);
            aQ[ks] = a;
        }
    }

    // row_rand for this lane's 4 output rows (C/D layout: row = quad*4 + rg)
    float rr[4];
    for (int rg = 0; rg < 4; ++rg) rr[rg] = RR[i0w + quad * 4 + rg];

    f32x4 accO[4];   // 16 rows x 64 d output accumulator (4 col-subtiles)
    for (int ds = 0; ds < 4; ++ds) accO[ds] = (f32x4){0.f, 0.f, 0.f, 0.f};

    int lsum = 0;    // per-lane sum of r (exact: r are small integers)

    for (int jt = 0; jt < NTILES; ++jt) {
        const int j0 = ic * JCHUNK + jt * JT;
        __syncthreads();  // protect LDS overwrite vs previous iter's readers

        // --- stage K tile (row-major) and V tile (transposed) into LDS as bf16 ---
        for (int it = 0; it < 4; ++it) {
            int f4  = tid + it * 256;        // 1024 float4 units = 64x64 elems
            int row = f4 >> 4;               // local j
            int col = (f4 & 15) * 4;         // k (for K) / d (for V)
            const float4 kv = *(const float4*)(Kf + (size_t)(j0 + row) * D + col);
            u16x4 kp;
            kp[0] = f2bf(kv.x); kp[1] = f2bf(kv.y);
            kp[2] = f2bf(kv.z); kp[3] = f2bf(kv.w);
            *(u16x4*)&kb[row * LDP + col] = kp;
            const float4 vv = *(const float4*)(V + (size_t)(j0 + row) * D + col);
            vt[(col + 0) * LDP + row] = (short)f2bf(vv.x);
            vt[(col + 1) * LDP + row] = (short)f2bf(vv.y);
            vt[(col + 2) * LDP + row] = (short)f2bf(vv.z);
            vt[(col + 3) * LDP + row] = (short)f2bf(vv.w);
        }
        __syncthreads();

        // --- QK^T: wave computes its 16 rows x 64 j (4 col-subtiles x 2 K-steps) ---
        f32x4 accqk[4];
        for (int cs = 0; cs < 4; ++cs) {
            f32x4 acc = (f32x4){0.f, 0.f, 0.f, 0.f};
            for (int ks = 0; ks < 2; ++ks) {
                s16x8 b = *(const s16x8*)&kb[(cs * 16 + n16) * LDP + ks * 32 + quad * 8];
                acc = __builtin_amdgcn_mfma_f32_16x16x32_bf16(aQ[ks], b, acc, 0, 0, 0);
            }
            accqk[cs] = acc;
        }

        // --- epilogue: dropout + floor mask; p = t*r -> bf16 into per-wave LDS ---
        short* pw = pb + w * (16 * LDP);
        for (int cs = 0; cs < 4; ++cs) {
            const int j = j0 + cs * 16 + n16;
            for (int rg = 0; rg < 4; ++rg) {
                const int irow = quad * 4 + rg;
                const float uval = Ud[(size_t)(i0w + irow) * S + j];
                // SCALE = 8 (sqrt(d)) * 1/0.9 (inverted dropout)
                const float t = (uval >= 0.1f) ? accqk[cs][rg] * (8.0f / 0.9f) : 0.0f;
                const float r = floorf(t * rr[rg]);
                lsum += (int)r;                       // exact small integer
                pw[irow * LDP + cs * 16 + n16] = (short)f2bf(t * r);
            }
        }
        __syncthreads();  // make pb visible (cross-lane) before A-frag reads

        // --- PV: accO[m][d] += P(16x64) @ V(64x64)  (B from transposed vt) ---
        for (int ksj = 0; ksj < 2; ++ksj) {
            s16x8 aP = *(const s16x8*)&pw[n16 * LDP + ksj * 32 + quad * 8];
            for (int ds = 0; ds < 4; ++ds) {
                s16x8 bV = *(const s16x8*)&vt[(ds * 16 + n16) * LDP + ksj * 32 + quad * 8];
                accO[ds] = __builtin_amdgcn_mfma_f32_16x16x32_bf16(aP, bV, accO[ds], 0, 0, 0);
            }
        }
    }

    // --- write numerator partials (8 chunks contend lightly per address) ---
    for (int ds = 0; ds < 4; ++ds) {
        const int d = ds * 16 + n16;
        for (int rg = 0; rg < 4; ++rg) {
            const int i = i0w + quad * 4 + rg;
            unsafeAtomicAdd(&out[(size_t)i * D + d], accO[ds][rg]);
        }
    }

    // --- reduce sum(r): wave shuffle -> LDS -> one int atomic per block ---
    for (int off = 32; off; off >>= 1) lsum += __shfl_down(lsum, off);
    if (lane == 0) red[w] = lsum;
    __syncthreads();
    if (tid == 0) atomicAdd(sumr, red[0] + red[1] + red[2] + red[3]);
}

__global__ void scale_kernel(float* __restrict__ out, const int* __restrict__ sumr) {
    const int idx = blockIdx.x * blockDim.x + threadIdx.x;
    // |R| ~ 7.5e6 < 2^24: int->float exact
    const float invR = 1.0f / (float)(*sumr);
    if (idx < S * D) out[idx] *= invR;
}

extern "C" void kernel_launch(void* const* d_in, const int* in_sizes, int n_in,
                              void* d_out, int out_size, void* d_ws, size_t ws_size,
                              hipStream_t stream) {
    (void)in_sizes; (void)n_in; (void)out_size; (void)ws_size;
    const float* Q  = (const float*)d_in[0];
    const float* Kf = (const float*)d_in[1];
    const float* V  = (const float*)d_in[2];
    const float* Ud = (const float*)d_in[3];
    const float* RR = (const float*)d_in[4];
    // d_in[5] ("x") is unused by the reference.
    float* out = (float*)d_out;
    int* sumr  = (int*)d_ws;

    hipMemsetAsync(d_out, 0, (size_t)S * D * sizeof(float), stream);
    hipMemsetAsync(d_ws, 0, sizeof(int), stream);
    fused_kernel<<<dim3(64 * NCHUNK), dim3(256), 0, stream>>>(Q, Kf, V, Ud, RR, out, sumr);
    scale_kernel<<<dim3((S * D) / 256), dim3(256), 0, stream>>>(out, sumr);
}